// Round 2
// baseline (617.006 us; speedup 1.0000x reference)
//
#include <hip/hip_runtime.h>
#include <hip/hip_bf16.h>

// ScaledDotProductAttention: B=16, N=2048, D=64. q/k/v fp32, mask int32,
// out fp32 (per reference dtypes; harness passes them raw).
// scores = q@k^T / sqrt(N); masked -> -1000; softmax over dim=1 (over n!);
// out = attn @ v.
// Softmax over n == column-wise normalization. Scores are tiny (|s| <~ 2),
// so exp without max-subtraction is safe; masked entries contribute exactly 0
// (reference's exp(-1000-max) underflows to 0 in fp32 too).
//
// Pass 1: colsum[b,m] = sum_n (mask ? 0 : exp(s))   (bf16 MFMA QK^T)
// Pass 2: out[b,n,:]  = sum_m (mask ? 0 : exp(s))/colsum[m] * v[m,:]
// Inputs converted fp32->bf16 (RNE) on the fly for MFMA; 2%-of-absmax
// threshold leaves ample budget (bf16 error on p ~0.8%, cancels via colsum).

#define B_ 16
#define N_ 2048
#define D_ 64
#define SCALE 0.022097086912079608f  // 1/sqrt(2048)

typedef __attribute__((ext_vector_type(8))) short bf16x8;
typedef __attribute__((ext_vector_type(4))) float f32x4;

static __device__ __forceinline__ short f2bf(float x) {
  // round-to-nearest-even fp32 -> bf16 (inputs are finite; no NaN handling)
  unsigned u = __float_as_uint(x);
  return (short)((u + 0x7FFF + ((u >> 16) & 1)) >> 16);
}

static __device__ __forceinline__ bf16x8 load8f(const float* p) {
  const f32x4 a = *reinterpret_cast<const f32x4*>(p);
  const f32x4 b = *reinterpret_cast<const f32x4*>(p + 4);
  bf16x8 r;
  r[0] = f2bf(a[0]); r[1] = f2bf(a[1]); r[2] = f2bf(a[2]); r[3] = f2bf(a[3]);
  r[4] = f2bf(b[0]); r[5] = f2bf(b[1]); r[6] = f2bf(b[2]); r[7] = f2bf(b[3]);
  return r;
}

// ---------------- Pass 1: column sums of P = exp(S) with mask ----------------
// Block: 256 threads = 4 waves; each wave owns 16 columns (m) and iterates the
// full n range. Block covers a 64-column stripe -> mask reads are 256B rows.
__global__ __launch_bounds__(256) void colsum_kernel(
    const float* __restrict__ q, const float* __restrict__ k,
    const int* __restrict__ mask, float* __restrict__ colsum) {
  const int b = blockIdx.x;
  const int wave = threadIdx.x >> 6;
  const int lane = threadIdx.x & 63;
  const int l15 = lane & 15;
  const int lhi = lane >> 4;
  const int m0 = blockIdx.y * 64 + wave * 16;

  const float* qb = q + (size_t)b * N_ * D_;
  const float* kb = k + (size_t)b * N_ * D_;
  const int* maskb = mask + (size_t)b * N_ * N_;

  // B-fragment of QK^T: B[kf][m] = K[m0+l15][kf], kf = lhi*8+j (+32). Fixed.
  const bf16x8 kf0 = load8f(kb + (m0 + l15) * D_ + lhi * 8);
  const bf16x8 kf1 = load8f(kb + (m0 + l15) * D_ + 32 + lhi * 8);

  float partial = 0.f;
  for (int n0 = 0; n0 < N_; n0 += 16) {
    // A-fragment: A[n0+l15][kf], 8 contiguous floats -> bf16.
    bf16x8 qf0 = load8f(qb + (n0 + l15) * D_ + lhi * 8);
    bf16x8 qf1 = load8f(qb + (n0 + l15) * D_ + 32 + lhi * 8);
    f32x4 acc = {0.f, 0.f, 0.f, 0.f};
    acc = __builtin_amdgcn_mfma_f32_16x16x32_bf16(qf0, kf0, acc, 0, 0, 0);
    acc = __builtin_amdgcn_mfma_f32_16x16x32_bf16(qf1, kf1, acc, 0, 0, 0);
    // C/D layout (verified m89): col = lane&15 (m), row = (lane>>4)*4+r (n).
#pragma unroll
    for (int r = 0; r < 4; ++r) {
      const int n = n0 + lhi * 4 + r;
      const int msk = maskb[(size_t)n * N_ + m0 + l15];
      partial += msk ? 0.f : __expf(acc[r] * SCALE);
    }
  }
  // Lanes {l15, l15+16, l15+32, l15+48} hold partials of the same column m.
  partial += __shfl_xor(partial, 16, 64);
  partial += __shfl_xor(partial, 32, 64);
  if (lane < 16) colsum[(size_t)b * N_ + m0 + l15] = partial;
}

// ---------------- Pass 2: out = (P / colsum) @ V ----------------
// Block: 256 threads = 4 waves, 64 output rows (16 per wave), all 64 d.
// Loop m in steps of 32: recompute P tile (16x32) via 4 MFMAs, write to
// per-wave LDS (C-layout -> [n][m]), read back as PV A-fragment (K=32),
// gather V B-fragments from global, 4 PV MFMAs into 4 d-subtile accumulators.
__global__ __launch_bounds__(256) void attn_out_kernel(
    const float* __restrict__ q, const float* __restrict__ k,
    const float* __restrict__ v, const int* __restrict__ mask,
    const float* __restrict__ colsum, float* __restrict__ out) {
  const int b = blockIdx.x;
  const int wave = threadIdx.x >> 6;
  const int lane = threadIdx.x & 63;
  const int l15 = lane & 15;
  const int lhi = lane >> 4;
  const int n0 = blockIdx.y * 64 + wave * 16;

  const float* qb = q + (size_t)b * N_ * D_;
  const float* kb = k + (size_t)b * N_ * D_;
  const float* vb = v + (size_t)b * N_ * D_;
  const int* maskb = mask + (size_t)b * N_ * N_;
  const float* csb = colsum + (size_t)b * N_;

  // Q fragments fixed for this wave's 16 rows.
  const bf16x8 qf0 = load8f(qb + (n0 + l15) * D_ + lhi * 8);
  const bf16x8 qf1 = load8f(qb + (n0 + l15) * D_ + 32 + lhi * 8);

  __shared__ __align__(16) short pbuf[4][16][32];

  f32x4 oacc[4];
#pragma unroll
  for (int d = 0; d < 4; ++d) oacc[d] = (f32x4){0.f, 0.f, 0.f, 0.f};

  for (int m0 = 0; m0 < N_; m0 += 32) {
#pragma unroll
    for (int cg = 0; cg < 2; ++cg) {
      const int mc = m0 + cg * 16;
      bf16x8 kf0 = load8f(kb + (mc + l15) * D_ + lhi * 8);
      bf16x8 kf1 = load8f(kb + (mc + l15) * D_ + 32 + lhi * 8);
      f32x4 acc = {0.f, 0.f, 0.f, 0.f};
      acc = __builtin_amdgcn_mfma_f32_16x16x32_bf16(qf0, kf0, acc, 0, 0, 0);
      acc = __builtin_amdgcn_mfma_f32_16x16x32_bf16(qf1, kf1, acc, 0, 0, 0);
      const float ic = 1.0f / csb[mc + l15];
#pragma unroll
      for (int r = 0; r < 4; ++r) {
        const int n = n0 + lhi * 4 + r;
        const int msk = maskb[(size_t)n * N_ + mc + l15];
        const float p = msk ? 0.f : __expf(acc[r] * SCALE) * ic;
        pbuf[wave][lhi * 4 + r][cg * 16 + l15] = f2bf(p);
      }
    }
    __syncthreads();  // conservative (pbuf is wave-local); cheap vs mask BW
    // A-fragment of PV: A[n=l15][mk=lhi*8+j] -> contiguous 16B in pbuf.
    const bf16x8 pa =
        *reinterpret_cast<const bf16x8*>(&pbuf[wave][l15][lhi * 8]);
#pragma unroll
    for (int dsub = 0; dsub < 4; ++dsub) {
      bf16x8 vf;
#pragma unroll
      for (int j = 0; j < 8; ++j) {
        // B[km][d] = V[m0 + lhi*8 + j][dsub*16 + l15]
        vf[j] = f2bf(vb[(m0 + lhi * 8 + j) * D_ + dsub * 16 + l15]);
      }
      oacc[dsub] =
          __builtin_amdgcn_mfma_f32_16x16x32_bf16(pa, vf, oacc[dsub], 0, 0, 0);
    }
    __syncthreads();  // protect pbuf from next iteration's writes
  }

#pragma unroll
  for (int dsub = 0; dsub < 4; ++dsub) {
#pragma unroll
    for (int r = 0; r < 4; ++r) {
      out[(size_t)b * N_ * D_ + (size_t)(n0 + lhi * 4 + r) * D_ + dsub * 16 +
          l15] = oacc[dsub][r];
    }
  }
}

extern "C" void kernel_launch(void* const* d_in, const int* in_sizes, int n_in,
                              void* d_out, int out_size, void* d_ws,
                              size_t ws_size, hipStream_t stream) {
  const float* q = (const float*)d_in[0];
  const float* k = (const float*)d_in[1];
  const float* v = (const float*)d_in[2];
  const int* mask = (const int*)d_in[3];
  float* colsum = (float*)d_ws;  // 16*2048 floats = 128 KB
  float* out = (float*)d_out;

  colsum_kernel<<<dim3(B_, N_ / 64), 256, 0, stream>>>(q, k, mask, colsum);
  attn_out_kernel<<<dim3(B_, N_ / 64), 256, 0, stream>>>(q, k, v, mask, colsum,
                                                         out);
}

// Round 3
// 557.333 us; speedup vs baseline: 1.1071x; 1.1071x over previous
//
#include <hip/hip_runtime.h>
#include <hip/hip_bf16.h>

// ScaledDotProductAttention: B=16, N=2048, D=64. q/k/v fp32, mask int32,
// out fp32. scores = q@k^T/sqrt(N); masked -> -1000; softmax over dim=1
// (COLUMN-wise over n); out = attn @ v.
// Column softmax: out[n,d] = sum_m exp(s[n,m])*[!mask]* (v[m,d]/colsum[m]).
// Scores tiny (|s|<~2) -> exp w/o max-subtraction safe; masked entries
// contribute exactly 0 (ref's exp(-1000-max) underflows in fp32 too).
//
// R3 structure (workspace precompute; R2 kernels kept as fallback):
//   1. pack_mask: 268 MB int32 mask -> 8 MB bitmask (the one HBM sweep)
//   2. cvt:       q,k fp32 -> bf16 row-major (4 MB each)
//   3. colsum:    colsum[b,m] = sum_n exp(s) * !mask   (MFMA, bitmask)
//   4. vprep:     vt[b][d][m] = bf16( v[b][m][d] / colsum[b][m] )  (transposed
//                 so PV B-fragments are contiguous 16B loads)
//   5. attn_out:  recompute P tile, wave-private LDS C->A relayout, PV MFMA

#define B_ 16
#define N_ 2048
#define D_ 64
#define SCALE 0.022097086912079608f  // 1/sqrt(2048)
#define NWORD (N_ / 32)              // 64 bitmask words per row

typedef __attribute__((ext_vector_type(8))) short bf16x8;
typedef __attribute__((ext_vector_type(4))) float f32x4;

static __device__ __forceinline__ short f2bf(float x) {
  unsigned u = __float_as_uint(x);
  return (short)((u + 0x7FFF + ((u >> 16) & 1)) >> 16);
}

static __device__ __forceinline__ bf16x8 load8(const short* p) {
  return *reinterpret_cast<const bf16x8*>(p);
}

static __device__ __forceinline__ bf16x8 load8f(const float* p) {
  const f32x4 a = *reinterpret_cast<const f32x4*>(p);
  const f32x4 b = *reinterpret_cast<const f32x4*>(p + 4);
  bf16x8 r;
  r[0] = f2bf(a[0]); r[1] = f2bf(a[1]); r[2] = f2bf(a[2]); r[3] = f2bf(a[3]);
  r[4] = f2bf(b[0]); r[5] = f2bf(b[1]); r[6] = f2bf(b[2]); r[7] = f2bf(b[3]);
  return r;
}

// ---------------- 1. pack mask to bits: word w covers mask[w*32 .. +31] ----
__global__ __launch_bounds__(256) void pack_mask(const int* __restrict__ mask,
                                                 unsigned* __restrict__ bits) {
  const size_t w = (size_t)blockIdx.x * 256 + threadIdx.x;
  const int4* p = reinterpret_cast<const int4*>(mask) + w * 8;
  unsigned r = 0;
#pragma unroll
  for (int j = 0; j < 8; ++j) {
    const int4 x = p[j];
    r |= (x.x ? 1u : 0u) << (j * 4);
    r |= (x.y ? 1u : 0u) << (j * 4 + 1);
    r |= (x.z ? 1u : 0u) << (j * 4 + 2);
    r |= (x.w ? 1u : 0u) << (j * 4 + 3);
  }
  bits[w] = r;
}

// ---------------- 2. fp32 -> bf16 convert (q: y=0, k: y=1) ----------------
__global__ __launch_bounds__(256) void cvt_bf16(const float* __restrict__ q,
                                                const float* __restrict__ k,
                                                short* __restrict__ qb,
                                                short* __restrict__ kb) {
  const size_t i = ((size_t)blockIdx.x * 256 + threadIdx.x) * 8;
  const float* src = blockIdx.y ? k : q;
  short* dst = blockIdx.y ? kb : qb;
  *reinterpret_cast<bf16x8*>(dst + i) = load8f(src + i);
}

// ---------------- 3. colsum[b,m] = sum_n !mask * exp(s) ----------------
// 4 waves/block; each wave owns 32 columns, iterates full n.
__global__ __launch_bounds__(256) void colsum_kernel(
    const short* __restrict__ qb, const short* __restrict__ kb,
    const unsigned* __restrict__ bits, float* __restrict__ colsum) {
  const int b = blockIdx.x;
  const int wave = threadIdx.x >> 6;
  const int lane = threadIdx.x & 63;
  const int l15 = lane & 15;
  const int lhi = lane >> 4;
  const int m0 = blockIdx.y * 128 + wave * 32;  // 32-aligned
  const int wword = m0 >> 5;

  const short* qbb = qb + (size_t)b * N_ * D_;
  const short* kbb = kb + (size_t)b * N_ * D_;
  const unsigned* bitsb = bits + (size_t)b * N_ * NWORD;

  bf16x8 kf[2][2];
#pragma unroll
  for (int cg = 0; cg < 2; ++cg) {
    kf[cg][0] = load8(kbb + (m0 + cg * 16 + l15) * D_ + lhi * 8);
    kf[cg][1] = load8(kbb + (m0 + cg * 16 + l15) * D_ + 32 + lhi * 8);
  }

  float part[2] = {0.f, 0.f};
  for (int n0 = 0; n0 < N_; n0 += 16) {
    const bf16x8 qf0 = load8(qbb + (n0 + l15) * D_ + lhi * 8);
    const bf16x8 qf1 = load8(qbb + (n0 + l15) * D_ + 32 + lhi * 8);
    unsigned w[4];
#pragma unroll
    for (int r = 0; r < 4; ++r) w[r] = bitsb[(n0 + lhi * 4 + r) * NWORD + wword];
#pragma unroll
    for (int cg = 0; cg < 2; ++cg) {
      f32x4 acc = {0.f, 0.f, 0.f, 0.f};
      acc = __builtin_amdgcn_mfma_f32_16x16x32_bf16(qf0, kf[cg][0], acc, 0, 0, 0);
      acc = __builtin_amdgcn_mfma_f32_16x16x32_bf16(qf1, kf[cg][1], acc, 0, 0, 0);
#pragma unroll
      for (int r = 0; r < 4; ++r) {
        const unsigned msk = (w[r] >> (cg * 16 + l15)) & 1u;
        part[cg] += msk ? 0.f : __expf(acc[r] * SCALE);
      }
    }
  }
#pragma unroll
  for (int cg = 0; cg < 2; ++cg) {
    float p = part[cg];
    p += __shfl_xor(p, 16, 64);
    p += __shfl_xor(p, 32, 64);
    if (lane < 16) colsum[(size_t)b * N_ + m0 + cg * 16 + l15] = p;
  }
}

// ---------------- 4. vt[b][d][m] = bf16(v[b][m][d] / colsum[b][m]) --------
__global__ __launch_bounds__(256) void vprep_kernel(
    const float* __restrict__ v, const float* __restrict__ colsum,
    short* __restrict__ vt) {
  const int b = blockIdx.x;
  const int m0 = blockIdx.y * 64;
  const int tid = threadIdx.x;
  __shared__ float lds[64][65];

  const float* vb = v + (size_t)b * N_ * D_;
  const float* csb = colsum + (size_t)b * N_;
#pragma unroll
  for (int pass = 0; pass < 4; ++pass) {
    const int mloc = pass * 16 + (tid >> 4);
    const int d4 = (tid & 15) * 4;
    const f32x4 x = *reinterpret_cast<const f32x4*>(vb + (m0 + mloc) * D_ + d4);
    const float ic = 1.0f / csb[m0 + mloc];
    lds[mloc][d4 + 0] = x[0] * ic;
    lds[mloc][d4 + 1] = x[1] * ic;
    lds[mloc][d4 + 2] = x[2] * ic;
    lds[mloc][d4 + 3] = x[3] * ic;
  }
  __syncthreads();
  const int d = tid >> 2;
  const int seg = tid & 3;
  bf16x8 o0, o1;
#pragma unroll
  for (int i = 0; i < 8; ++i) o0[i] = f2bf(lds[seg * 16 + i][d]);
#pragma unroll
  for (int i = 0; i < 8; ++i) o1[i] = f2bf(lds[seg * 16 + 8 + i][d]);
  short* dst = vt + (size_t)b * D_ * N_ + (size_t)d * N_ + m0 + seg * 16;
  *reinterpret_cast<bf16x8*>(dst) = o0;
  *reinterpret_cast<bf16x8*>(dst + 8) = o1;
}

// ---------------- 5. out = P @ Vt ----------------
// 4 waves/block, 16 n-rows per wave; m-loop step 32. pbuf is wave-private ->
// wave-local LDS ordering (no block barrier).
__global__ __launch_bounds__(256) void attn_out_kernel(
    const short* __restrict__ qb, const short* __restrict__ kb,
    const short* __restrict__ vt, const unsigned* __restrict__ bits,
    float* __restrict__ out) {
  const int b = blockIdx.x;
  const int wave = threadIdx.x >> 6;
  const int lane = threadIdx.x & 63;
  const int l15 = lane & 15;
  const int lhi = lane >> 4;
  const int n0 = blockIdx.y * 64 + wave * 16;

  const short* qbb = qb + (size_t)b * N_ * D_;
  const short* kbb = kb + (size_t)b * N_ * D_;
  const short* vtb = vt + (size_t)b * D_ * N_;
  const unsigned* bitsb = bits + (size_t)b * N_ * NWORD;

  const bf16x8 qf0 = load8(qbb + (n0 + l15) * D_ + lhi * 8);
  const bf16x8 qf1 = load8(qbb + (n0 + l15) * D_ + 32 + lhi * 8);

  __shared__ __align__(16) short pbuf[4][16][32];

  f32x4 oacc[4];
#pragma unroll
  for (int d = 0; d < 4; ++d) oacc[d] = (f32x4){0.f, 0.f, 0.f, 0.f};

  for (int m0 = 0; m0 < N_; m0 += 32) {
    unsigned w[4];
#pragma unroll
    for (int r = 0; r < 4; ++r)
      w[r] = bitsb[(n0 + lhi * 4 + r) * NWORD + (m0 >> 5)];
#pragma unroll
    for (int cg = 0; cg < 2; ++cg) {
      const int mc = m0 + cg * 16;
      const bf16x8 kf0 = load8(kbb + (mc + l15) * D_ + lhi * 8);
      const bf16x8 kf1 = load8(kbb + (mc + l15) * D_ + 32 + lhi * 8);
      f32x4 acc = {0.f, 0.f, 0.f, 0.f};
      acc = __builtin_amdgcn_mfma_f32_16x16x32_bf16(qf0, kf0, acc, 0, 0, 0);
      acc = __builtin_amdgcn_mfma_f32_16x16x32_bf16(qf1, kf1, acc, 0, 0, 0);
#pragma unroll
      for (int r = 0; r < 4; ++r) {
        const unsigned msk = (w[r] >> (cg * 16 + l15)) & 1u;
        const float p = msk ? 0.f : __expf(acc[r] * SCALE);
        pbuf[wave][lhi * 4 + r][cg * 16 + l15] = f2bf(p);
      }
    }
    // pbuf is wave-private: wave-local ordering suffices (LDS pipe is
    // in-order per wave; pin compiler order + drain writes).
    __builtin_amdgcn_wave_barrier();
    asm volatile("s_waitcnt lgkmcnt(0)" ::: "memory");
    const bf16x8 pa =
        *reinterpret_cast<const bf16x8*>(&pbuf[wave][l15][lhi * 8]);
#pragma unroll
    for (int dsub = 0; dsub < 4; ++dsub) {
      const bf16x8 vf =
          load8(vtb + (size_t)(dsub * 16 + l15) * N_ + m0 + lhi * 8);
      oacc[dsub] =
          __builtin_amdgcn_mfma_f32_16x16x32_bf16(pa, vf, oacc[dsub], 0, 0, 0);
    }
    __builtin_amdgcn_wave_barrier();
    asm volatile("" ::: "memory");  // keep next iter's writes after pa read
  }

#pragma unroll
  for (int dsub = 0; dsub < 4; ++dsub)
#pragma unroll
    for (int r = 0; r < 4; ++r)
      out[(size_t)b * N_ * D_ + (size_t)(n0 + lhi * 4 + r) * D_ + dsub * 16 +
          l15] = oacc[dsub][r];
}

// ================= R2 fallback (small-workspace path), verified ============
__global__ __launch_bounds__(256) void colsum_fb(
    const float* __restrict__ q, const float* __restrict__ k,
    const int* __restrict__ mask, float* __restrict__ colsum) {
  const int b = blockIdx.x;
  const int wave = threadIdx.x >> 6;
  const int lane = threadIdx.x & 63;
  const int l15 = lane & 15;
  const int lhi = lane >> 4;
  const int m0 = blockIdx.y * 64 + wave * 16;
  const float* qbp = q + (size_t)b * N_ * D_;
  const float* kbp = k + (size_t)b * N_ * D_;
  const int* maskb = mask + (size_t)b * N_ * N_;
  const bf16x8 kf0 = load8f(kbp + (m0 + l15) * D_ + lhi * 8);
  const bf16x8 kf1 = load8f(kbp + (m0 + l15) * D_ + 32 + lhi * 8);
  float partial = 0.f;
  for (int n0 = 0; n0 < N_; n0 += 16) {
    bf16x8 qf0 = load8f(qbp + (n0 + l15) * D_ + lhi * 8);
    bf16x8 qf1 = load8f(qbp + (n0 + l15) * D_ + 32 + lhi * 8);
    f32x4 acc = {0.f, 0.f, 0.f, 0.f};
    acc = __builtin_amdgcn_mfma_f32_16x16x32_bf16(qf0, kf0, acc, 0, 0, 0);
    acc = __builtin_amdgcn_mfma_f32_16x16x32_bf16(qf1, kf1, acc, 0, 0, 0);
#pragma unroll
    for (int r = 0; r < 4; ++r) {
      const int n = n0 + lhi * 4 + r;
      partial += maskb[(size_t)n * N_ + m0 + l15] ? 0.f
                                                  : __expf(acc[r] * SCALE);
    }
  }
  partial += __shfl_xor(partial, 16, 64);
  partial += __shfl_xor(partial, 32, 64);
  if (lane < 16) colsum[(size_t)b * N_ + m0 + l15] = partial;
}

__global__ __launch_bounds__(256) void attn_out_fb(
    const float* __restrict__ q, const float* __restrict__ k,
    const float* __restrict__ v, const int* __restrict__ mask,
    const float* __restrict__ colsum, float* __restrict__ out) {
  const int b = blockIdx.x;
  const int wave = threadIdx.x >> 6;
  const int lane = threadIdx.x & 63;
  const int l15 = lane & 15;
  const int lhi = lane >> 4;
  const int n0 = blockIdx.y * 64 + wave * 16;
  const float* qbp = q + (size_t)b * N_ * D_;
  const float* kbp = k + (size_t)b * N_ * D_;
  const float* vbp = v + (size_t)b * N_ * D_;
  const int* maskb = mask + (size_t)b * N_ * N_;
  const float* csb = colsum + (size_t)b * N_;
  const bf16x8 qf0 = load8f(qbp + (n0 + l15) * D_ + lhi * 8);
  const bf16x8 qf1 = load8f(qbp + (n0 + l15) * D_ + 32 + lhi * 8);
  __shared__ __align__(16) short pbuf[4][16][32];
  f32x4 oacc[4];
#pragma unroll
  for (int d = 0; d < 4; ++d) oacc[d] = (f32x4){0.f, 0.f, 0.f, 0.f};
  for (int m0 = 0; m0 < N_; m0 += 32) {
#pragma unroll
    for (int cg = 0; cg < 2; ++cg) {
      const int mc = m0 + cg * 16;
      bf16x8 kf0 = load8f(kbp + (mc + l15) * D_ + lhi * 8);
      bf16x8 kf1 = load8f(kbp + (mc + l15) * D_ + 32 + lhi * 8);
      f32x4 acc = {0.f, 0.f, 0.f, 0.f};
      acc = __builtin_amdgcn_mfma_f32_16x16x32_bf16(qf0, kf0, acc, 0, 0, 0);
      acc = __builtin_amdgcn_mfma_f32_16x16x32_bf16(qf1, kf1, acc, 0, 0, 0);
      const float ic = 1.0f / csb[mc + l15];
#pragma unroll
      for (int r = 0; r < 4; ++r) {
        const int n = n0 + lhi * 4 + r;
        const float p = maskb[(size_t)n * N_ + mc + l15]
                            ? 0.f
                            : __expf(acc[r] * SCALE) * ic;
        pbuf[wave][lhi * 4 + r][cg * 16 + l15] = f2bf(p);
      }
    }
    __syncthreads();
    const bf16x8 pa =
        *reinterpret_cast<const bf16x8*>(&pbuf[wave][l15][lhi * 8]);
#pragma unroll
    for (int dsub = 0; dsub < 4; ++dsub) {
      bf16x8 vf;
#pragma unroll
      for (int j = 0; j < 8; ++j)
        vf[j] = f2bf(vbp[(m0 + lhi * 8 + j) * D_ + dsub * 16 + l15]);
      oacc[dsub] =
          __builtin_amdgcn_mfma_f32_16x16x32_bf16(pa, vf, oacc[dsub], 0, 0, 0);
    }
    __syncthreads();
  }
#pragma unroll
  for (int dsub = 0; dsub < 4; ++dsub)
#pragma unroll
    for (int r = 0; r < 4; ++r)
      out[(size_t)b * N_ * D_ + (size_t)(n0 + lhi * 4 + r) * D_ + dsub * 16 +
          l15] = oacc[dsub][r];
}

extern "C" void kernel_launch(void* const* d_in, const int* in_sizes, int n_in,
                              void* d_out, int out_size, void* d_ws,
                              size_t ws_size, hipStream_t stream) {
  const float* q = (const float*)d_in[0];
  const float* k = (const float*)d_in[1];
  const float* v = (const float*)d_in[2];
  const int* mask = (const int*)d_in[3];
  float* out = (float*)d_out;

  // workspace layout
  const size_t cs_off = 0;                         // 128 KB colsum
  const size_t qb_off = 128 * 1024;                // 4 MB qbf
  const size_t kb_off = qb_off + 4 * 1024 * 1024;  // 4 MB kbf
  const size_t vt_off = kb_off + 4 * 1024 * 1024;  // 4 MB vt
  const size_t bt_off = vt_off + 4 * 1024 * 1024;  // 8 MB bits
  const size_t need = bt_off + 8 * 1024 * 1024;

  float* colsum = (float*)((char*)d_ws + cs_off);

  if (ws_size >= need) {
    short* qbf = (short*)((char*)d_ws + qb_off);
    short* kbf = (short*)((char*)d_ws + kb_off);
    short* vt = (short*)((char*)d_ws + vt_off);
    unsigned* bits = (unsigned*)((char*)d_ws + bt_off);

    pack_mask<<<(B_ * N_ * NWORD) / 256, 256, 0, stream>>>(mask, bits);
    cvt_bf16<<<dim3((B_ * N_ * D_) / (256 * 8), 2), 256, 0, stream>>>(
        q, k, qbf, kbf);
    colsum_kernel<<<dim3(B_, N_ / 128), 256, 0, stream>>>(qbf, kbf, bits,
                                                          colsum);
    vprep_kernel<<<dim3(B_, N_ / 64), 256, 0, stream>>>(v, colsum, vt);
    attn_out_kernel<<<dim3(B_, N_ / 64), 256, 0, stream>>>(qbf, kbf, vt, bits,
                                                           out);
  } else {
    colsum_fb<<<dim3(B_, N_ / 64), 256, 0, stream>>>(q, k, mask, colsum);
    attn_out_fb<<<dim3(B_, N_ / 64), 256, 0, stream>>>(q, k, v, mask, colsum,
                                                       out);
  }
}

// Round 4
// 542.395 us; speedup vs baseline: 1.1376x; 1.0275x over previous
//
#include <hip/hip_runtime.h>
#include <hip/hip_bf16.h>

// ScaledDotProductAttention: B=16, N=2048, D=64. q/k/v fp32, mask int32,
// out fp32. scores = q@k^T/sqrt(N); masked -> -1000; softmax over dim=1
// (COLUMN-wise over n); out = attn @ v.
// out[n,d] = sum_m exp(s[n,m])*[!mask] * (v[m,d]/colsum[m]).
//
// R4: R3 structure + occupancy fix (R3 was latency-bound at 1-2 waves/SIMD):
//   colsum split 4x over n (partials, summed in vprep)
//   attn_out split 4x over m (partial outputs in ws + reduce kernel)
//   -> 8 waves/SIMD on the hot kernel.

#define B_ 16
#define N_ 2048
#define D_ 64
#define SCALE 0.022097086912079608f  // 1/sqrt(2048)
#define NWORD (N_ / 32)              // 64 bitmask words per row
#define MCH 4                        // m-chunks for attn_out
#define NCH 4                        // n-chunks for colsum

typedef __attribute__((ext_vector_type(8))) short bf16x8;
typedef __attribute__((ext_vector_type(4))) float f32x4;

static __device__ __forceinline__ short f2bf(float x) {
  unsigned u = __float_as_uint(x);
  return (short)((u + 0x7FFF + ((u >> 16) & 1)) >> 16);
}

static __device__ __forceinline__ bf16x8 load8(const short* p) {
  return *reinterpret_cast<const bf16x8*>(p);
}

static __device__ __forceinline__ bf16x8 load8f(const float* p) {
  const f32x4 a = *reinterpret_cast<const f32x4*>(p);
  const f32x4 b = *reinterpret_cast<const f32x4*>(p + 4);
  bf16x8 r;
  r[0] = f2bf(a[0]); r[1] = f2bf(a[1]); r[2] = f2bf(a[2]); r[3] = f2bf(a[3]);
  r[4] = f2bf(b[0]); r[5] = f2bf(b[1]); r[6] = f2bf(b[2]); r[7] = f2bf(b[3]);
  return r;
}

// ---------------- 1. pack mask to bits ----------------
__global__ __launch_bounds__(256) void pack_mask(const int* __restrict__ mask,
                                                 unsigned* __restrict__ bits) {
  const size_t w = (size_t)blockIdx.x * 256 + threadIdx.x;
  const int4* p = reinterpret_cast<const int4*>(mask) + w * 8;
  unsigned r = 0;
#pragma unroll
  for (int j = 0; j < 8; ++j) {
    const int4 x = p[j];
    r |= (x.x ? 1u : 0u) << (j * 4);
    r |= (x.y ? 1u : 0u) << (j * 4 + 1);
    r |= (x.z ? 1u : 0u) << (j * 4 + 2);
    r |= (x.w ? 1u : 0u) << (j * 4 + 3);
  }
  bits[w] = r;
}

// ---------------- 2. fp32 -> bf16 convert (q: y=0, k: y=1) ----------------
__global__ __launch_bounds__(256) void cvt_bf16(const float* __restrict__ q,
                                                const float* __restrict__ k,
                                                short* __restrict__ qb,
                                                short* __restrict__ kb) {
  const size_t i = ((size_t)blockIdx.x * 256 + threadIdx.x) * 8;
  const float* src = blockIdx.y ? k : q;
  short* dst = blockIdx.y ? kb : qb;
  *reinterpret_cast<bf16x8*>(dst + i) = load8f(src + i);
}

// ------- 3. colsum partials: csp[z][b][m] = sum_{n in chunk z} !mask*exp(s)
// grid (B, N/128, NCH); 4 waves/block, wave owns 32 columns, 512 n-rows.
__global__ __launch_bounds__(256) void colsum_kernel(
    const short* __restrict__ qb, const short* __restrict__ kb,
    const unsigned* __restrict__ bits, float* __restrict__ csp) {
  const int b = blockIdx.x;
  const int wave = threadIdx.x >> 6;
  const int lane = threadIdx.x & 63;
  const int l15 = lane & 15;
  const int lhi = lane >> 4;
  const int m0 = blockIdx.y * 128 + wave * 32;
  const int wword = m0 >> 5;
  const int nbase = blockIdx.z * (N_ / NCH);

  const short* qbb = qb + (size_t)b * N_ * D_;
  const short* kbb = kb + (size_t)b * N_ * D_;
  const unsigned* bitsb = bits + (size_t)b * N_ * NWORD;

  bf16x8 kf[2][2];
#pragma unroll
  for (int cg = 0; cg < 2; ++cg) {
    kf[cg][0] = load8(kbb + (m0 + cg * 16 + l15) * D_ + lhi * 8);
    kf[cg][1] = load8(kbb + (m0 + cg * 16 + l15) * D_ + 32 + lhi * 8);
  }

  float part[2] = {0.f, 0.f};
  for (int n0 = nbase; n0 < nbase + N_ / NCH; n0 += 16) {
    const bf16x8 qf0 = load8(qbb + (n0 + l15) * D_ + lhi * 8);
    const bf16x8 qf1 = load8(qbb + (n0 + l15) * D_ + 32 + lhi * 8);
    unsigned w[4];
#pragma unroll
    for (int r = 0; r < 4; ++r)
      w[r] = bitsb[(n0 + lhi * 4 + r) * NWORD + wword];
#pragma unroll
    for (int cg = 0; cg < 2; ++cg) {
      f32x4 acc = {0.f, 0.f, 0.f, 0.f};
      acc = __builtin_amdgcn_mfma_f32_16x16x32_bf16(qf0, kf[cg][0], acc, 0, 0, 0);
      acc = __builtin_amdgcn_mfma_f32_16x16x32_bf16(qf1, kf[cg][1], acc, 0, 0, 0);
#pragma unroll
      for (int r = 0; r < 4; ++r) {
        const unsigned msk = (w[r] >> (cg * 16 + l15)) & 1u;
        part[cg] += msk ? 0.f : __expf(acc[r] * SCALE);
      }
    }
  }
#pragma unroll
  for (int cg = 0; cg < 2; ++cg) {
    float p = part[cg];
    p += __shfl_xor(p, 16, 64);
    p += __shfl_xor(p, 32, 64);
    if (lane < 16)
      csp[(size_t)blockIdx.z * B_ * N_ + (size_t)b * N_ + m0 + cg * 16 + l15] =
          p;
  }
}

// ------- 4. vt[b][d][m] = bf16(v[b][m][d] / sum_z csp[z][b][m]) -------
__global__ __launch_bounds__(256) void vprep_kernel(
    const float* __restrict__ v, const float* __restrict__ csp,
    short* __restrict__ vt) {
  const int b = blockIdx.x;
  const int m0 = blockIdx.y * 64;
  const int tid = threadIdx.x;
  __shared__ float lds[64][65];

  const float* vb = v + (size_t)b * N_ * D_;
#pragma unroll
  for (int pass = 0; pass < 4; ++pass) {
    const int mloc = pass * 16 + (tid >> 4);
    const int d4 = (tid & 15) * 4;
    const f32x4 x = *reinterpret_cast<const f32x4*>(vb + (m0 + mloc) * D_ + d4);
    float cs = 0.f;
#pragma unroll
    for (int z = 0; z < NCH; ++z)
      cs += csp[(size_t)z * B_ * N_ + (size_t)b * N_ + m0 + mloc];
    const float ic = 1.0f / cs;
    lds[mloc][d4 + 0] = x[0] * ic;
    lds[mloc][d4 + 1] = x[1] * ic;
    lds[mloc][d4 + 2] = x[2] * ic;
    lds[mloc][d4 + 3] = x[3] * ic;
  }
  __syncthreads();
  const int d = tid >> 2;
  const int seg = tid & 3;
  bf16x8 o0, o1;
#pragma unroll
  for (int i = 0; i < 8; ++i) o0[i] = f2bf(lds[seg * 16 + i][d]);
#pragma unroll
  for (int i = 0; i < 8; ++i) o1[i] = f2bf(lds[seg * 16 + 8 + i][d]);
  short* dst = vt + (size_t)b * D_ * N_ + (size_t)d * N_ + m0 + seg * 16;
  *reinterpret_cast<bf16x8*>(dst) = o0;
  *reinterpret_cast<bf16x8*>(dst + 8) = o1;
}

// ------- 5. partial out: outp[z] += P(:, mchunk z) @ Vt(mchunk z, :) -------
// grid (B, N/64, MCH); 4 waves/block, 16 n-rows per wave, 512 m per block.
__global__ __launch_bounds__(256) void attn_out_kernel(
    const short* __restrict__ qb, const short* __restrict__ kb,
    const short* __restrict__ vt, const unsigned* __restrict__ bits,
    float* __restrict__ outp) {
  const int b = blockIdx.x;
  const int wave = threadIdx.x >> 6;
  const int lane = threadIdx.x & 63;
  const int l15 = lane & 15;
  const int lhi = lane >> 4;
  const int n0 = blockIdx.y * 64 + wave * 16;
  const int mbase = blockIdx.z * (N_ / MCH);

  const short* qbb = qb + (size_t)b * N_ * D_;
  const short* kbb = kb + (size_t)b * N_ * D_;
  const short* vtb = vt + (size_t)b * D_ * N_;
  const unsigned* bitsb = bits + (size_t)b * N_ * NWORD;

  const bf16x8 qf0 = load8(qbb + (n0 + l15) * D_ + lhi * 8);
  const bf16x8 qf1 = load8(qbb + (n0 + l15) * D_ + 32 + lhi * 8);

  __shared__ __align__(16) short pbuf[4][16][32];

  f32x4 oacc[4];
#pragma unroll
  for (int d = 0; d < 4; ++d) oacc[d] = (f32x4){0.f, 0.f, 0.f, 0.f};

  for (int m0 = mbase; m0 < mbase + N_ / MCH; m0 += 32) {
    unsigned w[4];
#pragma unroll
    for (int r = 0; r < 4; ++r)
      w[r] = bitsb[(n0 + lhi * 4 + r) * NWORD + (m0 >> 5)];
#pragma unroll
    for (int cg = 0; cg < 2; ++cg) {
      const int mc = m0 + cg * 16;
      const bf16x8 kf0 = load8(kbb + (mc + l15) * D_ + lhi * 8);
      const bf16x8 kf1 = load8(kbb + (mc + l15) * D_ + 32 + lhi * 8);
      f32x4 acc = {0.f, 0.f, 0.f, 0.f};
      acc = __builtin_amdgcn_mfma_f32_16x16x32_bf16(qf0, kf0, acc, 0, 0, 0);
      acc = __builtin_amdgcn_mfma_f32_16x16x32_bf16(qf1, kf1, acc, 0, 0, 0);
#pragma unroll
      for (int r = 0; r < 4; ++r) {
        const unsigned msk = (w[r] >> (cg * 16 + l15)) & 1u;
        const float p = msk ? 0.f : __expf(acc[r] * SCALE);
        pbuf[wave][lhi * 4 + r][cg * 16 + l15] = f2bf(p);
      }
    }
    // pbuf is wave-private: wave-local ordering suffices.
    __builtin_amdgcn_wave_barrier();
    asm volatile("s_waitcnt lgkmcnt(0)" ::: "memory");
    const bf16x8 pa =
        *reinterpret_cast<const bf16x8*>(&pbuf[wave][l15][lhi * 8]);
#pragma unroll
    for (int dsub = 0; dsub < 4; ++dsub) {
      const bf16x8 vf =
          load8(vtb + (size_t)(dsub * 16 + l15) * N_ + m0 + lhi * 8);
      oacc[dsub] =
          __builtin_amdgcn_mfma_f32_16x16x32_bf16(pa, vf, oacc[dsub], 0, 0, 0);
    }
    __builtin_amdgcn_wave_barrier();
  }

  float* dst = outp + (size_t)blockIdx.z * B_ * N_ * D_ + (size_t)b * N_ * D_;
#pragma unroll
  for (int dsub = 0; dsub < 4; ++dsub)
#pragma unroll
    for (int r = 0; r < 4; ++r)
      dst[(size_t)(n0 + lhi * 4 + r) * D_ + dsub * 16 + l15] = oacc[dsub][r];
}

// ---------------- 6. reduce the MCH partial outputs ----------------
__global__ __launch_bounds__(256) void reduce_out(const float* __restrict__ outp,
                                                  float* __restrict__ out) {
  const size_t i = ((size_t)blockIdx.x * 256 + threadIdx.x) * 4;
  f32x4 s = *reinterpret_cast<const f32x4*>(outp + i);
#pragma unroll
  for (int z = 1; z < MCH; ++z) {
    const f32x4 x =
        *reinterpret_cast<const f32x4*>(outp + (size_t)z * B_ * N_ * D_ + i);
    s[0] += x[0]; s[1] += x[1]; s[2] += x[2]; s[3] += x[3];
  }
  *reinterpret_cast<f32x4*>(out + i) = s;
}

// ================= R2 fallback (small-workspace path), verified ============
__global__ __launch_bounds__(256) void colsum_fb(
    const float* __restrict__ q, const float* __restrict__ k,
    const int* __restrict__ mask, float* __restrict__ colsum) {
  const int b = blockIdx.x;
  const int wave = threadIdx.x >> 6;
  const int lane = threadIdx.x & 63;
  const int l15 = lane & 15;
  const int lhi = lane >> 4;
  const int m0 = blockIdx.y * 64 + wave * 16;
  const float* qbp = q + (size_t)b * N_ * D_;
  const float* kbp = k + (size_t)b * N_ * D_;
  const int* maskb = mask + (size_t)b * N_ * N_;
  const bf16x8 kf0 = load8f(kbp + (m0 + l15) * D_ + lhi * 8);
  const bf16x8 kf1 = load8f(kbp + (m0 + l15) * D_ + 32 + lhi * 8);
  float partial = 0.f;
  for (int n0 = 0; n0 < N_; n0 += 16) {
    bf16x8 qf0 = load8f(qbp + (n0 + l15) * D_ + lhi * 8);
    bf16x8 qf1 = load8f(qbp + (n0 + l15) * D_ + 32 + lhi * 8);
    f32x4 acc = {0.f, 0.f, 0.f, 0.f};
    acc = __builtin_amdgcn_mfma_f32_16x16x32_bf16(qf0, kf0, acc, 0, 0, 0);
    acc = __builtin_amdgcn_mfma_f32_16x16x32_bf16(qf1, kf1, acc, 0, 0, 0);
#pragma unroll
    for (int r = 0; r < 4; ++r) {
      const int n = n0 + lhi * 4 + r;
      partial +=
          maskb[(size_t)n * N_ + m0 + l15] ? 0.f : __expf(acc[r] * SCALE);
    }
  }
  partial += __shfl_xor(partial, 16, 64);
  partial += __shfl_xor(partial, 32, 64);
  if (lane < 16) colsum[(size_t)b * N_ + m0 + l15] = partial;
}

__global__ __launch_bounds__(256) void attn_out_fb(
    const float* __restrict__ q, const float* __restrict__ k,
    const float* __restrict__ v, const int* __restrict__ mask,
    const float* __restrict__ colsum, float* __restrict__ out) {
  const int b = blockIdx.x;
  const int wave = threadIdx.x >> 6;
  const int lane = threadIdx.x & 63;
  const int l15 = lane & 15;
  const int lhi = lane >> 4;
  const int n0 = blockIdx.y * 64 + wave * 16;
  const float* qbp = q + (size_t)b * N_ * D_;
  const float* kbp = k + (size_t)b * N_ * D_;
  const float* vbp = v + (size_t)b * N_ * D_;
  const int* maskb = mask + (size_t)b * N_ * N_;
  const float* csb = colsum + (size_t)b * N_;
  const bf16x8 qf0 = load8f(qbp + (n0 + l15) * D_ + lhi * 8);
  const bf16x8 qf1 = load8f(qbp + (n0 + l15) * D_ + 32 + lhi * 8);
  __shared__ __align__(16) short pbuf[4][16][32];
  f32x4 oacc[4];
#pragma unroll
  for (int d = 0; d < 4; ++d) oacc[d] = (f32x4){0.f, 0.f, 0.f, 0.f};
  for (int m0 = 0; m0 < N_; m0 += 32) {
#pragma unroll
    for (int cg = 0; cg < 2; ++cg) {
      const int mc = m0 + cg * 16;
      bf16x8 kf0 = load8f(kbp + (mc + l15) * D_ + lhi * 8);
      bf16x8 kf1 = load8f(kbp + (mc + l15) * D_ + 32 + lhi * 8);
      f32x4 acc = {0.f, 0.f, 0.f, 0.f};
      acc = __builtin_amdgcn_mfma_f32_16x16x32_bf16(qf0, kf0, acc, 0, 0, 0);
      acc = __builtin_amdgcn_mfma_f32_16x16x32_bf16(qf1, kf1, acc, 0, 0, 0);
      const float ic = 1.0f / csb[mc + l15];
#pragma unroll
      for (int r = 0; r < 4; ++r) {
        const int n = n0 + lhi * 4 + r;
        const float p = maskb[(size_t)n * N_ + mc + l15]
                            ? 0.f
                            : __expf(acc[r] * SCALE) * ic;
        pbuf[wave][lhi * 4 + r][cg * 16 + l15] = f2bf(p);
      }
    }
    __syncthreads();
    const bf16x8 pa =
        *reinterpret_cast<const bf16x8*>(&pbuf[wave][l15][lhi * 8]);
#pragma unroll
    for (int dsub = 0; dsub < 4; ++dsub) {
      bf16x8 vf;
#pragma unroll
      for (int j = 0; j < 8; ++j)
        vf[j] = f2bf(vbp[(m0 + lhi * 8 + j) * D_ + dsub * 16 + l15]);
      oacc[dsub] =
          __builtin_amdgcn_mfma_f32_16x16x32_bf16(pa, vf, oacc[dsub], 0, 0, 0);
    }
    __syncthreads();
  }
#pragma unroll
  for (int dsub = 0; dsub < 4; ++dsub)
#pragma unroll
    for (int r = 0; r < 4; ++r)
      out[(size_t)b * N_ * D_ + (size_t)(n0 + lhi * 4 + r) * D_ + dsub * 16 +
          l15] = oacc[dsub][r];
}

extern "C" void kernel_launch(void* const* d_in, const int* in_sizes, int n_in,
                              void* d_out, int out_size, void* d_ws,
                              size_t ws_size, hipStream_t stream) {
  const float* q = (const float*)d_in[0];
  const float* k = (const float*)d_in[1];
  const float* v = (const float*)d_in[2];
  const int* mask = (const int*)d_in[3];
  float* out = (float*)d_out;

  // workspace layout
  const size_t MB = 1024 * 1024;
  const size_t cs_off = 0;                  // NCH*128 KB colsum partials
  const size_t qb_off = cs_off + NCH * (size_t)B_ * N_ * 4;  // 4 MB
  const size_t kb_off = qb_off + 4 * MB;
  const size_t vt_off = kb_off + 4 * MB;
  const size_t bt_off = vt_off + 4 * MB;    // 8 MB bits
  const size_t op_off = bt_off + 8 * MB;    // MCH*8 MB out partials
  const size_t need = op_off + (size_t)MCH * B_ * N_ * D_ * 4;

  if (ws_size >= need) {
    float* csp = (float*)((char*)d_ws + cs_off);
    short* qbf = (short*)((char*)d_ws + qb_off);
    short* kbf = (short*)((char*)d_ws + kb_off);
    short* vt = (short*)((char*)d_ws + vt_off);
    unsigned* bits = (unsigned*)((char*)d_ws + bt_off);
    float* outp = (float*)((char*)d_ws + op_off);

    pack_mask<<<(B_ * N_ * NWORD) / 256, 256, 0, stream>>>(mask, bits);
    cvt_bf16<<<dim3((B_ * N_ * D_) / (256 * 8), 2), 256, 0, stream>>>(
        q, k, qbf, kbf);
    colsum_kernel<<<dim3(B_, N_ / 128, NCH), 256, 0, stream>>>(qbf, kbf, bits,
                                                               csp);
    vprep_kernel<<<dim3(B_, N_ / 64), 256, 0, stream>>>(v, csp, vt);
    attn_out_kernel<<<dim3(B_, N_ / 64, MCH), 256, 0, stream>>>(qbf, kbf, vt,
                                                                bits, outp);
    reduce_out<<<(B_ * N_ * D_) / (256 * 4), 256, 0, stream>>>(outp, out);
  } else {
    float* colsum = (float*)d_ws;  // 128 KB
    colsum_fb<<<dim3(B_, N_ / 64), 256, 0, stream>>>(q, k, mask, colsum);
    attn_out_fb<<<dim3(B_, N_ / 64), 256, 0, stream>>>(q, k, v, mask, colsum,
                                                       out);
  }
}